// Round 14
// baseline (307.559 us; speedup 1.0000x reference)
//
#include <hip/hip_runtime.h>
#include <stdint.h>
#include <math.h>

#define B_   4
#define T_   4096
#define BT_  16384
#define HID  2048
#define ED   256
#define HD   32
#define NH   8
#define K3   768    // packed split K (hi|hi|lo)
#define KW   6144   // packed split K for W2 = Wo@Wv (hi|hi|lo over 2048)
#define KSP  8      // K-split for W2 GEMM
#define NP   9      // per-row gamma partials {A1,A2,A3,A4,A5,X1,X2,S1,S2}

typedef unsigned short u16;
typedef __attribute__((ext_vector_type(8))) short short8;
typedef __attribute__((ext_vector_type(4))) float f32x4;

typedef __attribute__((address_space(1))) void gvoid;
typedef __attribute__((address_space(3))) void lvoid;

__device__ __forceinline__ float bf2f(u16 h) {
    return __uint_as_float(((uint32_t)h) << 16);
}
__device__ __forceinline__ u16 f2bf(float f) {
    uint32_t u = __float_as_uint(f);
    u += 0x7FFFu + ((u >> 16) & 1u);   // round-to-nearest-even
    return (u16)(u >> 16);
}
__device__ __forceinline__ void gld_lds16(const void* g, void* l) {
    __builtin_amdgcn_global_load_lds((gvoid*)(uintptr_t)g, (lvoid*)(uintptr_t)l, 16, 0, 0);
}
__device__ __forceinline__ void BAR() {
    asm volatile("" ::: "memory");
    __builtin_amdgcn_s_barrier();
    asm volatile("" ::: "memory");
}

// ---- Wk -> packed [hi | lo | hi] rows of 768 (pairs with A3 = [hi | hi | lo]) ----
__global__ void k_cvt_wk3(const float* __restrict__ in, u16* __restrict__ out) {
    int i = blockIdx.x * 256 + threadIdx.x;   // over HID*ED
    int n = i >> 8, c = i & 255;
    float f = in[i];
    u16 h = f2bf(f);
    out[(size_t)n * K3 + c]       = h;
    out[(size_t)n * K3 + 256 + c] = f2bf(f - bf2f(h));
    out[(size_t)n * K3 + 512 + c] = h;
}

// ---- Wo (2048x2048 f32) -> WoP [2048][6144] = [hi | hi | lo] ----
__global__ void k_packWo(const float* __restrict__ wo, u16* __restrict__ wop) {
    int i = blockIdx.x * 256 + threadIdx.x;   // over 2048*2048
    int o = i >> 11, n = i & 2047;
    float f = wo[i];
    u16 h = f2bf(f);
    wop[(size_t)o * KW + n]        = h;
    wop[(size_t)o * KW + 2048 + n] = h;
    wop[(size_t)o * KW + 4096 + n] = f2bf(f - bf2f(h));
}

// ---- Wv (2048x256 f32, row n col c) -> WvP [256][6144] = [hi | lo | hi] (transposed) ----
__global__ void k_packWv(const float* __restrict__ wv, u16* __restrict__ wvp) {
    int i = blockIdx.x * 256 + threadIdx.x;   // over 2048*256
    int n = i >> 8, c = i & 255;
    float f = wv[i];
    u16 h = f2bf(f);
    wvp[(size_t)c * KW + n]        = h;
    wvp[(size_t)c * KW + 2048 + n] = f2bf(f - bf2f(h));
    wvp[(size_t)c * KW + 4096 + n] = h;
}

// ---- reduce 8 K-split partials -> W2 f32 -> W23 [2048][768] = [hi | lo | hi] ----
__global__ void k_w2pack(const float* __restrict__ part, u16* __restrict__ w23) {
    int i = blockIdx.x * 256 + threadIdx.x;   // over 2048*256
    int o = i >> 8, c = i & 255;
    float s = 0.f;
#pragma unroll
    for (int k = 0; k < KSP; ++k) s += part[(size_t)k * HID * ED + i];
    u16 h = f2bf(s);
    w23[(size_t)o * K3 + c]       = h;
    w23[(size_t)o * K3 + 256 + c] = f2bf(s - bf2f(h));
    w23[(size_t)o * K3 + 512 + c] = h;
}

// ---------------- hash-embedding gather (f32) ----------------
__global__ void k_gather(const int* __restrict__ hashes, const int* __restrict__ offs,
                         const float* __restrict__ tab, float* __restrict__ E) {
    const int bt = blockIdx.x;
    const int tid = threadIdx.x;          // 256 = 8 heads x 32 dims
    const int head = tid >> 5, d = tid & 31;
    const int row = hashes[bt * NH + head] + offs[head];
    E[(size_t)bt * ED + tid] = tab[(size_t)row * HD + d];
}

// ---- conv + LN + silu + residual; writes A3 row = [e_hi | e_hi | e_lo] (768) ----
__global__ void k_conv(const float* __restrict__ E, const float* __restrict__ w,
                       const float* __restrict__ lng, const float* __restrict__ lnb,
                       u16* __restrict__ a3) {
    const int bt = blockIdx.x;
    const int b = bt >> 12;               // T_ = 4096
    const int t = bt & 4095;
    const int ch = threadIdx.x;           // 256
    float c = 0.f;
#pragma unroll
    for (int k = 0; k < 4; ++k) {
        int tt = t - 9 + 3 * k;           // taps at t-9, t-6, t-3, t
        if (tt >= 0)
            c += w[ch * 4 + k] * E[((size_t)(b * T_ + tt)) * ED + ch];
    }
    float s = c, s2 = c * c;
#pragma unroll
    for (int o = 32; o; o >>= 1) { s += __shfl_xor(s, o); s2 += __shfl_xor(s2, o); }
    __shared__ float red[8];
    const int wid = ch >> 6, lane = ch & 63;
    if (!lane) { red[wid] = s; red[4 + wid] = s2; }
    __syncthreads();
    s  = red[0] + red[1] + red[2] + red[3];
    s2 = red[4] + red[5] + red[6] + red[7];
    const float mean = s * (1.f / 256.f);
    const float var  = s2 * (1.f / 256.f) - mean * mean;
    float ln = (c - mean) * rsqrtf(var + 1e-5f) * lng[ch] + lnb[ch];
    float si = ln / (1.f + expf(-ln));    // silu
    float ev = E[(size_t)bt * ED + ch] + si;
    u16 h = f2bf(ev);
    a3[(size_t)bt * K3 + ch]       = h;
    a3[(size_t)bt * K3 + 256 + ch] = h;
    a3[(size_t)bt * K3 + 512 + ch] = f2bf(ev - bf2f(h));
}

// ---- column constants: C1=sum gq*gk, C2=sum gq*bk, C3=sum bq*gk, C4=sum bq*bk ----
__global__ void k_consts(const float* __restrict__ gq, const float* __restrict__ bq,
                         const float* __restrict__ gk, const float* __restrict__ bk,
                         float* __restrict__ consts) {
    const int tid = threadIdx.x;          // 256 thr, 8 cols each
    float c1 = 0.f, c2 = 0.f, c3 = 0.f, c4 = 0.f;
#pragma unroll
    for (int i = 0; i < 8; ++i) {
        const int n = tid + i * 256;
        const float a = gq[n], b = bq[n], g = gk[n], d = bk[n];
        c1 += a * g; c2 += a * d; c3 += b * g; c4 += b * d;
    }
#pragma unroll
    for (int o = 32; o; o >>= 1) {
        c1 += __shfl_xor(c1, o); c2 += __shfl_xor(c2, o);
        c3 += __shfl_xor(c3, o); c4 += __shfl_xor(c4, o);
    }
    __shared__ float red[16];
    const int wid = tid >> 6, lane = tid & 63;
    if (!lane) { red[wid] = c1; red[4 + wid] = c2; red[8 + wid] = c3; red[12 + wid] = c4; }
    __syncthreads();
    if (tid == 0) {
        consts[0] = red[0] + red[1] + red[2] + red[3];
        consts[1] = red[4] + red[5] + red[6] + red[7];
        consts[2] = red[8] + red[9] + red[10] + red[11];
        consts[3] = red[12] + red[13] + red[14] + red[15];
    }
}

// ---------------- finalize gamma from 8 partial slices of 9 sums ----------------
// dot = rx*rk*(A1 - muk*A2 - mux*A3 + mux*muk*C1) + rx*(A4 - mux*C2)
//     + rk*(A5 - muk*C3) + C4
__global__ void k_gamma2(const float* __restrict__ partial, const float* __restrict__ consts,
                         float* __restrict__ gamma) {
    const int m = blockIdx.x * 256 + threadIdx.x;
    float s[NP];
#pragma unroll
    for (int v = 0; v < NP; ++v) s[v] = 0.f;
    const float* p = partial + (size_t)m * (8 * NP);
#pragma unroll
    for (int nb = 0; nb < 8; ++nb)
#pragma unroll
        for (int v = 0; v < NP; ++v) s[v] += p[nb * NP + v];
    const float inv = 1.f / (float)HID;
    const float mux = s[5] * inv, vx = s[6] * inv - mux * mux;
    const float muk = s[7] * inv, vk = s[8] * inv - muk * muk;
    const float rx = rsqrtf(vx + 1e-5f), rk = rsqrtf(vk + 1e-5f);
    const float dot = rx * rk * (s[0] - muk * s[1] - mux * s[2] + mux * muk * consts[0])
                    + rx * (s[3] - mux * consts[1])
                    + rk * (s[4] - muk * consts[2])
                    + consts[3];
    const float gd = dot * 0.022097086912079608f;   // 1/sqrt(2048)
    const float sg = (gd > 0.f) ? 1.f : ((gd < 0.f) ? -1.f : 0.f);
    const float sv = sqrtf(fmaxf(fabsf(gd), 1e-6f)) * sg;
    gamma[m] = 1.f / (1.f + expf(-sv));
}

// ================= 256x256 / BK=64 bf16 MFMA GEMM — pipelined, chunk-aligned =================
// (r10/r11-validated core: chunk-pure reads, 4-phase staging, vmcnt(6).)
// A row = mh*128 + wr*64 + fm*16 + l15 (P1 reads exactly A h0, P3 exactly h1)
// B row = nh*128 + wc*32 + fn*16 + l15 (P1 reads exactly B h0, P2 exactly h1)
// Schedule (tile t, buf p=t&1): P1 reads Ah0,Bh0 + stage Ah1(t+1)->p^1; P2 reads
// Bh1 + stage Ah0(t+2)->p; P3 reads Ah1 + stage Bh0(t+2)->p; P4 regs-only +
// stage Bh1(t+2)->p + vmcnt(6) (drains ALL of t+1, issued 4-8 phases earlier).
// GRID=0: 2D XCD chunking (grid 64x8 tiles). GRID=1: row-major + K-split via
// blockIdx.y. EPI: 0 = f32 K-split slab; 2 = fused key->gamma 9-sum partials
// (key AND x-stats never materialized — r14 kills the k_xstat pass);
// 3 = f32 store with rowscale.
template <int EPI, int GRID>
__global__ __launch_bounds__(512, 2)
void gemm8(const u16* __restrict__ A, int lda, const u16* __restrict__ Bm, int ldb,
           const float* __restrict__ rowscale, void* __restrict__ Cout,
           int M, int N, int K,
           const float* __restrict__ xq,
           const float* __restrict__ gq, const float* __restrict__ bq,
           const float* __restrict__ gk, const float* __restrict__ bk,
           float* __restrict__ partial) {
    extern __shared__ char smem[];
    const int tid = threadIdx.x, wid = tid >> 6, lane = tid & 63;
    const int l15 = lane & 15, lhi = lane >> 4;
    const int wr = wid >> 2, wc = wid & 3;

    const int id = blockIdx.x;
    int mblk, nblk;
    if (GRID == 0) {
        // 2D XCD chunking: xcd = id&7 owns an 8(m) x 8(n) tile chunk
        const int xcd = id & 7, loc = id >> 3;
        mblk = ((xcd << 3) + (loc & 7)) << 8;
        nblk = (loc >> 3) << 8;
    } else {
        const int tiles_m = M >> 8;
        mblk = (id % tiles_m) << 8;
        nblk = (id / tiles_m) << 8;
        const size_t koff = (size_t)blockIdx.y * K;
        A  += koff;
        Bm += koff;
    }

    f32x4 acc[8][4];
#pragma unroll
    for (int i = 0; i < 8; ++i)
#pragma unroll
        for (int j = 0; j < 4; ++j) acc[i][j] = f32x4{0.f, 0.f, 0.f, 0.f};

    const int srow = tid >> 3;
    const int scol = ((tid & 7) << 3) ^ ((srow & 7) << 3);
    const u16* aS[4];
    const u16* bS[4];
#pragma unroll
    for (int h = 0; h < 2; ++h)
#pragma unroll
        for (int r = 0; r < 2; ++r) {
            aS[h * 2 + r] = A  + (size_t)(mblk + h * 128 + r * 64 + srow) * lda + scol;
            bS[h * 2 + r] = Bm + (size_t)(nblk + h * 128 + r * 64 + srow) * ldb + scol;
        }
    const int wb = wid * 1024;

    const int koff0 = (lhi * 16) ^ ((l15 & 7) << 4);
    const int koff1 = (64 + lhi * 16) ^ ((l15 & 7) << 4);

    short8 ar[4][2], br[2][2][2];

#define SA(h, tt) do { const int kk_ = (tt) << 6;                                    \
        char* d_ = smem + (((tt) & 1) * 32768) + (h) * 16384 + wb;                   \
        gld_lds16(aS[(h) * 2 + 0] + kk_, d_);                                        \
        gld_lds16(aS[(h) * 2 + 1] + kk_, d_ + 8192); } while (0)
#define SB(h, tt) do { const int kk_ = (tt) << 6;                                    \
        char* d_ = smem + 65536 + (((tt) & 1) * 32768) + (h) * 16384 + wb;           \
        gld_lds16(bS[(h) * 2 + 0] + kk_, d_);                                        \
        gld_lds16(bS[(h) * 2 + 1] + kk_, d_ + 8192); } while (0)
#define LDA_SUB(mh, p) do {                                                          \
        const char* ab_ = smem + (p) * 32768 + ((mh) * 128 + wr * 64) * 128;         \
        _Pragma("unroll") for (int fm = 0; fm < 4; ++fm) {                           \
            const char* rb_ = ab_ + (fm * 16 + l15) * 128;                           \
            ar[fm][0] = *(const short8*)(rb_ + koff0);                               \
            ar[fm][1] = *(const short8*)(rb_ + koff1); } } while (0)
#define LDB_SUB(nh, p) do {                                                          \
        const char* bb_ = smem + 65536 + (p) * 32768 + ((nh) * 128 + wc * 32) * 128; \
        _Pragma("unroll") for (int fn = 0; fn < 2; ++fn) {                           \
            const char* rb_ = bb_ + (fn * 16 + l15) * 128;                           \
            br[nh][fn][0] = *(const short8*)(rb_ + koff0);                           \
            br[nh][fn][1] = *(const short8*)(rb_ + koff1); } } while (0)
#define MMQ(mh, nh) do { __builtin_amdgcn_s_setprio(1);                              \
        _Pragma("unroll") for (int fm = 0; fm < 4; ++fm)                             \
        _Pragma("unroll") for (int fn = 0; fn < 2; ++fn) {                           \
            acc[(mh) * 4 + fm][(nh) * 2 + fn] = __builtin_amdgcn_mfma_f32_16x16x32_bf16( \
                ar[fm][0], br[nh][fn][0], acc[(mh) * 4 + fm][(nh) * 2 + fn], 0, 0, 0);   \
            acc[(mh) * 4 + fm][(nh) * 2 + fn] = __builtin_amdgcn_mfma_f32_16x16x32_bf16( \
                ar[fm][1], br[nh][fn][1], acc[(mh) * 4 + fm][(nh) * 2 + fn], 0, 0, 0); } \
        __builtin_amdgcn_s_setprio(0); } while (0)

    // prologue: tiles 0,1 fully staged (16 loads); drain tile 0 (oldest 8)
    SA(0, 0); SA(1, 0); SB(0, 0); SB(1, 0);
    SA(0, 1); SA(1, 1); SB(0, 1); SB(1, 1);
    asm volatile("s_waitcnt vmcnt(8)" ::: "memory");
    BAR();

    const int nk = K >> 6;
    for (int t = 0; t < nk; ++t) {
        const int p = t & 1;
        // P1: reads Ah0,Bh0 of buf p; stage Ah1(t+1) -> p^1 (freed (t-1).P3)
        LDA_SUB(0, p); LDB_SUB(0, p);
        if (t >= 1 && t + 1 < nk) SA(1, t + 1);
        BAR(); MMQ(0, 0); BAR();
        // P2: reads Bh1; stage Ah0(t+2) -> p (region freed at P1)
        LDB_SUB(1, p);
        if (t + 2 < nk) SA(0, t + 2);
        BAR(); MMQ(0, 1); BAR();
        // P3: reads Ah1; stage Bh0(t+2) -> p (freed at P1)
        LDA_SUB(1, p);
        if (t + 2 < nk) SB(0, t + 2);
        BAR(); MMQ(1, 0); BAR();
        // P4: regs only; stage Bh1(t+2) -> p (freed at P2); vmcnt(6) leaves the
        // 3 halves staged this tile, drains all of t+1
        if (t + 2 < nk) {
            SB(1, t + 2);
            asm volatile("s_waitcnt vmcnt(6)" ::: "memory");
        } else {
            asm volatile("s_waitcnt vmcnt(0)" ::: "memory");
        }
        BAR(); MMQ(1, 1); BAR();
    }
#undef SA
#undef SB
#undef LDA_SUB
#undef LDB_SUB
#undef MMQ

    if (EPI == 2) {
        // ---- fused key->gamma 9-sum partial reduction (key in registers;
        //      x-stats folded in — no separate k_xstat pass) ----
        float ggv[4], gbv[4], bgv[4];
#pragma unroll
        for (int nj = 0; nj < 4; ++nj) {
            const int n = nblk + (nj >> 1) * 128 + wc * 32 + (nj & 1) * 16 + l15;
            const float a = gq[n], b = bq[n], g = gk[n], d = bk[n];
            ggv[nj] = a * g; gbv[nj] = a * d; bgv[nj] = b * g;
        }
        float* red = (float*)smem;           // [256 rows][4 wc][9] = 36 KB
#pragma unroll
        for (int mi = 0; mi < 8; ++mi) {
#pragma unroll
            for (int rr = 0; rr < 4; ++rr) {
                const int rloc = (mi >> 2) * 128 + wr * 64 + (mi & 3) * 16 + lhi * 4 + rr;
                const int m = mblk + rloc;
                float v[NP];
#pragma unroll
                for (int q = 0; q < NP; ++q) v[q] = 0.f;
#pragma unroll
                for (int nj = 0; nj < 4; ++nj) {
                    const float kv = acc[mi][nj][rr];
                    const int n = nblk + (nj >> 1) * 128 + wc * 32 + (nj & 1) * 16 + l15;
                    const float xv = xq[(size_t)m * N + n];
                    const float xg = xv * ggv[nj];
                    v[0] += xg * kv;        // A1
                    v[1] += xg;             // A2
                    v[2] += ggv[nj] * kv;   // A3
                    v[3] += xv * gbv[nj];   // A4
                    v[4] += bgv[nj] * kv;   // A5
                    v[5] += xv;             // X1
                    v[6] += xv * xv;        // X2
                    v[7] += kv;             // S1
                    v[8] += kv * kv;        // S2
                }
#pragma unroll
                for (int o = 1; o < 16; o <<= 1)
#pragma unroll
                    for (int q = 0; q < NP; ++q) v[q] += __shfl_xor(v[q], o);
                if (l15 == 0) {
                    float* d = red + ((size_t)rloc * 4 + wc) * NP;
#pragma unroll
                    for (int q = 0; q < NP; ++q) d[q] = v[q];
                }
            }
        }
        BAR();
        const int nb = nblk >> 8;
        for (int e = tid; e < 256 * NP; e += 512) {
            const int row = e / NP, q = e - row * NP;
            const float s = red[((size_t)row * 4 + 0) * NP + q] + red[((size_t)row * 4 + 1) * NP + q]
                          + red[((size_t)row * 4 + 2) * NP + q] + red[((size_t)row * 4 + 3) * NP + q];
            partial[((size_t)(mblk + row) * 8 + nb) * NP + q] = s;
        }
    } else {
        // direct fragment epilogue: D row=(lane>>4)*4+r, col=lane&15
        float* Cf = (float*)Cout;
        if (EPI == 0 && GRID == 1) Cf += (size_t)blockIdx.y * M * N;   // K-split slab
#pragma unroll
        for (int mi = 0; mi < 8; ++mi) {
#pragma unroll
            for (int rr = 0; rr < 4; ++rr) {
                const int m = mblk + (mi >> 2) * 128 + wr * 64 + (mi & 3) * 16 + lhi * 4 + rr;
                const float sc = (EPI == 3) ? rowscale[m] : 1.0f;
#pragma unroll
                for (int nj = 0; nj < 4; ++nj) {
                    const int n = nblk + (nj >> 1) * 128 + wc * 32 + (nj & 1) * 16 + l15;
                    Cf[(size_t)m * N + n] = acc[mi][nj][rr] * sc;
                }
            }
        }
    }
}

extern "C" void kernel_launch(void* const* d_in, const int* in_sizes, int n_in,
                              void* d_out, int out_size, void* d_ws, size_t ws_size,
                              hipStream_t stream) {
    const float* x      = (const float*)d_in[0];
    const int*   hashes = (const int*)d_in[1];
    const int*   offs   = (const int*)d_in[2];
    const float* emb    = (const float*)d_in[3];
    const float* conv_w = (const float*)d_in[4];
    const float* lncg   = (const float*)d_in[5];
    const float* lncb   = (const float*)d_in[6];
    const float* Wk     = (const float*)d_in[7];
    const float* Wv     = (const float*)d_in[8];
    const float* Wo     = (const float*)d_in[9];
    const float* lnkg   = (const float*)d_in[10];
    const float* lnkb   = (const float*)d_in[11];
    const float* lnqg   = (const float*)d_in[12];
    const float* lnqb   = (const float*)d_in[13];

    // ws (~85 MB). E (16.8MB, dead after k_conv) aliases W2part. key/value/x-stats
    // never materialized: out = gamma * (e @ (Wo@Wv)^T).
    char* p = (char*)d_ws;
    float* E      = (float*)p;
    float* W2part = (float*)p;  p += (size_t)KSP * HID * ED * 4;  // 16.8 MB
    u16*   A3     = (u16*)p;    p += (size_t)BT_ * K3 * 2;        // 25.2 MB
    u16*   Wk3    = (u16*)p;    p += (size_t)HID * K3 * 2;        // 3.1 MB
    u16*   WoP    = (u16*)p;    p += (size_t)HID * KW * 2;        // 25.2 MB
    u16*   WvP    = (u16*)p;    p += (size_t)ED * KW * 2;         // 3.1 MB
    u16*   W23    = (u16*)p;    p += (size_t)HID * K3 * 2;        // 3.1 MB
    float* part   = (float*)p;  p += (size_t)BT_ * 8 * NP * 4;    // 4.7 MB
    float* consts = (float*)p;  p += 64;
    float* gamma  = (float*)p;  p += (size_t)BT_ * 4;             // 64 KB

    hipFuncSetAttribute((const void*)gemm8<0, 1>,
                        hipFuncAttributeMaxDynamicSharedMemorySize, 131072);
    hipFuncSetAttribute((const void*)gemm8<2, 0>,
                        hipFuncAttributeMaxDynamicSharedMemorySize, 131072);
    hipFuncSetAttribute((const void*)gemm8<3, 0>,
                        hipFuncAttributeMaxDynamicSharedMemorySize, 131072);

    k_cvt_wk3<<<(HID * ED) / 256, 256, 0, stream>>>(Wk, Wk3);
    k_packWo<<<(HID * HID) / 256, 256, 0, stream>>>(Wo, WoP);
    k_packWv<<<(HID * ED) / 256, 256, 0, stream>>>(Wv, WvP);
    k_gather<<<BT_, 256, 0, stream>>>(hashes, offs, emb, E);
    k_conv<<<BT_, 256, 0, stream>>>(E, conv_w, lncg, lncb, A3);
    k_consts<<<1, 256, 0, stream>>>(lnqg, lnqb, lnkg, lnkb, consts);

    // W2 = Wo @ Wv split-precision, K-split 8 x 768 -> f32 slabs (over dead E)
    gemm8<0, 1><<<dim3(HID / 256, KSP), 512, 131072, stream>>>(
        WoP, KW, WvP, KW, nullptr, W2part, HID, ED, KW / KSP,
        nullptr, nullptr, nullptr, nullptr, nullptr, nullptr);
    k_w2pack<<<(HID * ED) / 256, 256, 0, stream>>>(W2part, W23);

    const dim3 grid((BT_ / 256) * (HID / 256));   // 512 = 64x8 tiles
    // key partials: A3 @ Wk3^T (K=768), 9-sum gamma reduction fused in epilogue
    gemm8<2, 0><<<grid, 512, 131072, stream>>>(
        A3, K3, Wk3, K3, nullptr, nullptr, BT_, HID, K3,
        x, lnqg, lnqb, lnkg, lnkb, part);
    k_gamma2<<<BT_ / 256, 256, 0, stream>>>(part, consts, gamma);
    // out = gamma * (A3 @ W23^T)  (K=768) -> d_out f32
    gemm8<3, 0><<<grid, 512, 131072, stream>>>(
        A3, K3, W23, K3, gamma, d_out, BT_, HID, K3,
        nullptr, nullptr, nullptr, nullptr, nullptr, nullptr);
}